// Round 6
// baseline (413.588 us; speedup 1.0000x reference)
//
#include <hip/hip_runtime.h>
#include <stdint.h>

#define COLS 65536
#define KSEL 32
#define TPB 256
#define CAP 1024
#define PIV_HI 0xC0300000u   /* flip32(2.75f); rank-32/65536 threshold for N(0,1) ~ 3.30 */

typedef __attribute__((ext_vector_type(4))) float f32x4;

__device__ __forceinline__ uint32_t flip32(float f) {
    uint32_t u = __float_as_uint(f);
    return u ^ ((u & 0x80000000u) ? 0xFFFFFFFFu : 0x80000000u);
}
__device__ __forceinline__ float unflip32(uint32_t k) {
    uint32_t u = k ^ ((k & 0x80000000u) ? 0x80000000u : 0xFFFFFFFFu);
    return __uint_as_float(u);
}

// One block per row, copy-shaped with overlapped streams:
//   (0) NT zero-fill burst for this wave's quarter — issued FIRST so the store stream
//       drains under the whole read phase (barrier waits vmcnt(0) for both anyway)
//   (1) NT read stream + rare candidate capture into LDS (expected ~195 / 65536)
//   (2) per-wave bisection counting straight from LDS (no k[16] regs -> lower VGPR)
//   (3) scatter the 32 winners (zeros already drained at the barrier; cheap re-check)
// Key = (flip32(value) << 32) | (0xFFFF - col): strictly monotone in (value desc, col asc),
// all keys distinct => exact rank-32 boundary exists; matches jax.lax.top_k tie order.
__global__ __launch_bounds__(TPB)
void topk_onepass_kernel(const float* __restrict__ x, float* __restrict__ out) {
    __shared__ unsigned long long cand[CAP];   // 8 KiB
    __shared__ int s_cnt;

    const int row  = blockIdx.x;
    const int tid  = threadIdx.x;
    const int lane = tid & 63;
    const int wave = tid >> 6;

    if (tid == 0) s_cnt = 0;
    __syncthreads();

    const f32x4* __restrict__ xv = (const f32x4*)(x + (size_t)row * COLS);
    float* __restrict__ orow = out + (size_t)row * COLS;
    f32x4* __restrict__ ov = (f32x4*)orow;

    const int segBase4 = wave * 4096;                    // this wave's quarter (float4 units)
    const uint32_t segLo = (uint32_t)wave * 16384u, segHi = segLo + 16384u;
    const f32x4 z = (f32x4)(0.f);

    // ---- Phase 0: zero-store burst, drains under the read phase.
    #pragma unroll
    for (int i = 0; i < 64; ++i)
        __builtin_nontemporal_store(z, &ov[segBase4 + i * 64 + lane]);

    // ---- Phase 1: pure read stream + rare candidate capture into LDS.
    #pragma unroll 8
    for (int j = 0; j < COLS / 4 / TPB; ++j) {           // 64 coalesced float4 iters
        const int vi = j * TPB + tid;
        const f32x4 v = __builtin_nontemporal_load(&xv[vi]);
        const uint32_t f0 = flip32(v.x), f1 = flip32(v.y), f2 = flip32(v.z), f3 = flip32(v.w);
        const int n = (int)(f0 >= PIV_HI) + (int)(f1 >= PIV_HI)
                    + (int)(f2 >= PIV_HI) + (int)(f3 >= PIV_HI);
        if (n) {                                         // ~1.2% of lane-iterations
            int pos = atomicAdd(&s_cnt, n);              // LDS atomic, uncontended
            const uint32_t col0 = (uint32_t)vi << 2;
            const uint32_t fs[4] = {f0, f1, f2, f3};
            #pragma unroll
            for (int e = 0; e < 4; ++e) {
                if (fs[e] >= PIV_HI) {
                    if (pos < CAP)
                        cand[pos] = ((unsigned long long)fs[e] << 32)
                                  | (unsigned long long)(0xFFFFu - (col0 + e));
                    ++pos;
                }
            }
        }
    }
    __syncthreads();                                     // drains loads AND phase-0 stores
    const int c = s_cnt;

    if (c >= KSEL && c <= CAP) {
        // ---- Phase 2: per-wave redundant bisection counting from LDS.
        unsigned long long lo = ((unsigned long long)PIV_HI << 32) - 1ull;  // count(>lo)==c
        unsigned long long hi = ~0ull;
        unsigned long long mid = lo;
        int m = c;
        for (int it = 0; it < 72 && m != KSEL; ++it) {
            mid = lo + ((hi - lo) >> 1);
            int local = 0;
            #pragma unroll
            for (int i = 0; i < 16; ++i) {
                const int idx = i * 64 + lane;
                local += (int)(idx < c && cand[idx] > mid);
            }
            #pragma unroll
            for (int off = 32; off >= 1; off >>= 1) local += __shfl_xor(local, off, 64);
            m = local;
            if (m > KSEL) lo = mid; else if (m < KSEL) hi = mid;
        }

        // ---- Phase 3: scatter winners in my quarter (zeros drained at barrier; belt+braces).
        asm volatile("s_waitcnt vmcnt(0)" ::: "memory");
        for (int idx = lane; idx < c; idx += 64) {
            const unsigned long long key = cand[idx];
            if (key > mid) {
                const uint32_t col = 0xFFFFu - (uint32_t)(key & 0xFFFFull);
                if (col >= segLo && col < segHi)
                    orow[col] = fmaxf(unflip32((uint32_t)(key >> 32)), 0.f);
            }
        }
    } else {
        // Correctness fallback (P ~ 0 for N(0,1)): wave-redundant full-row bisection from
        // global, then scatter over my quarter. Zeros were already issued in phase 0.
        const float* __restrict__ xr = x + (size_t)row * COLS;
        unsigned long long lo = 0ull, hi = ~0ull, mid = 0ull;
        int m = -1;
        for (int it = 0; it < 96 && m != KSEL; ++it) {
            mid = lo + ((hi - lo) >> 1);
            int local = 0;
            for (int j = lane; j < COLS; j += 64) {
                const unsigned long long key =
                    ((unsigned long long)flip32(xr[j]) << 32)
                    | (unsigned long long)(0xFFFFu - (uint32_t)j);
                local += (int)(key > mid);
            }
            #pragma unroll
            for (int off = 32; off >= 1; off >>= 1) local += __shfl_xor(local, off, 64);
            m = local;
            if (m > KSEL) lo = mid; else if (m < KSEL) hi = mid;
        }
        asm volatile("s_waitcnt vmcnt(0)" ::: "memory");
        for (uint32_t j = segLo + lane; j < segHi; j += 64) {
            const float v = xr[j];
            const unsigned long long key =
                ((unsigned long long)flip32(v) << 32)
                | (unsigned long long)(0xFFFFu - j);
            if (key > mid) orow[j] = fmaxf(v, 0.f);
        }
    }
}

extern "C" void kernel_launch(void* const* d_in, const int* in_sizes, int n_in,
                              void* d_out, int out_size, void* d_ws, size_t ws_size,
                              hipStream_t stream) {
    const float* x = (const float*)d_in[0];
    float* out = (float*)d_out;
    const int rows = in_sizes[0] / COLS;
    topk_onepass_kernel<<<rows, TPB, 0, stream>>>(x, out);
}